// Round 5
// baseline (830.249 us; speedup 1.0000x reference)
//
#include <hip/hip_runtime.h>
#include <math.h>

#define Nn 30000
#define RR 3
#define EE 80000
#define MT_M 235      // ceil(Nn/128)

#define SAP 72        // padded LDS row stride (bf16 elems) for staged tiles
#define EP_LD 68      // per-wave epilogue scratch stride (floats)
#define UTS 136       // fused-gate U-tile LDS stride (128+8 -> 4-bank/row advance)
#define KBIG 0x40000000

typedef __attribute__((ext_vector_type(8))) short bf16x8;
typedef __attribute__((ext_vector_type(4))) float f32x4;

__device__ __forceinline__ unsigned short f2bf(float f) {
    union { float f; unsigned u; } v; v.f = f;
    unsigned r = v.u + 0x7fff + ((v.u >> 16) & 1);
    return (unsigned short)(r >> 16);
}
__device__ __forceinline__ float bf2f(short h) {
    union { unsigned u; float f; } v;
    v.u = ((unsigned)(unsigned short)h) << 16;
    return v.f;
}
__device__ __forceinline__ float fast_tanh(float x) {
    float e = __expf(2.f * x);
    return 1.f - 2.f / (e + 1.f);
}
__device__ __forceinline__ void unpack8(uint4 u, float* f) {
    union { unsigned u; float f; } a;
    a.u = u.x << 16;          f[0] = a.f;
    a.u = u.x & 0xffff0000u;  f[1] = a.f;
    a.u = u.y << 16;          f[2] = a.f;
    a.u = u.y & 0xffff0000u;  f[3] = a.f;
    a.u = u.z << 16;          f[4] = a.f;
    a.u = u.z & 0xffff0000u;  f[5] = a.f;
    a.u = u.w << 16;          f[6] = a.f;
    a.u = u.w & 0xffff0000u;  f[7] = a.f;
}

// ---------------------------------------------------------------------------
// LDS-staged MFMA GEMM core (128x128 tile, BK=64, 4 waves x 64x64).
// ---------------------------------------------------------------------------
__device__ __forceinline__ void mfma_core(
    const short* __restrict__ A, int lda,
    const short* __restrict__ A2, int lda2, int ksplit,
    const short* __restrict__ Bt,
    int M, int K, int m0, int n0,
    short* As, short* Bs, f32x4 (&acc)[4][4])
{
    const int t = threadIdx.x;
    const int srow = t >> 3;          // 0..31
    const int scol = (t & 7) << 3;    // 0..56 step 8
    const int lane = t & 63;
    const int wave = t >> 6;
    const int wm = (wave >> 1) << 6;
    const int wn = (wave & 1) << 6;
    const int fr = lane & 15;
    const int quad = lane >> 4;

    for (int k0 = 0; k0 < K; k0 += 64) {
        const short* Abase; int kk0, ldax;
        if (k0 < ksplit) { Abase = A;  kk0 = k0;          ldax = lda;  }
        else             { Abase = A2; kk0 = k0 - ksplit; ldax = lda2; }
        #pragma unroll
        for (int rr = 0; rr < 4; rr++) {
            int r = srow + rr * 32;
            int gr = m0 + r;
            bf16x8 va = {0, 0, 0, 0, 0, 0, 0, 0};
            if (gr < M) va = *(const bf16x8*)(Abase + (size_t)gr * ldax + kk0 + scol);
            *(bf16x8*)(As + r * SAP + scol) = va;
        }
        #pragma unroll
        for (int rr = 0; rr < 4; rr++) {
            int r = srow + rr * 32;
            bf16x8 vb = *(const bf16x8*)(Bt + (size_t)(n0 + r) * K + k0 + scol);
            *(bf16x8*)(Bs + r * SAP + scol) = vb;
        }
        __syncthreads();
        #pragma unroll
        for (int kc = 0; kc < 2; kc++) {
            bf16x8 af[4], bfr[4];
            #pragma unroll
            for (int i = 0; i < 4; i++)
                af[i] = *(const bf16x8*)(As + (wm + i * 16 + fr) * SAP + kc * 32 + quad * 8);
            #pragma unroll
            for (int i = 0; i < 4; i++)
                bfr[i] = *(const bf16x8*)(Bs + (wn + i * 16 + fr) * SAP + kc * 32 + quad * 8);
            #pragma unroll
            for (int mi = 0; mi < 4; mi++)
                #pragma unroll
                for (int ni = 0; ni < 4; ni++)
                    acc[mi][ni] = __builtin_amdgcn_mfma_f32_16x16x32_bf16(
                        af[mi], bfr[ni], acc[mi][ni], 0, 0, 0);
        }
        __syncthreads();
    }
}

// General GEMM: C = act(A @ Bt^T + bias). Wave-private LDS repack epilogue.
__global__ __launch_bounds__(256) void gemm_mfma(
    const short* __restrict__ A, int lda,
    const short* __restrict__ A2, int lda2, int ksplit,
    const short* __restrict__ Bt, const float* __restrict__ bias,
    float* __restrict__ C, int ldc, short* __restrict__ Cbf, int ldcbf,
    int M, int K, int act)
{
    __shared__ short As[128 * SAP];
    __shared__ short Bs[128 * SAP];
    f32x4 acc[4][4];
    #pragma unroll
    for (int i = 0; i < 4; i++)
        #pragma unroll
        for (int j = 0; j < 4; j++) acc[i][j] = (f32x4){0.f, 0.f, 0.f, 0.f};
    int m0 = blockIdx.y * 128, n0 = blockIdx.x * 128;
    mfma_core(A, lda, A2, lda2, ksplit, Bt, M, K, m0, n0, As, Bs, acc);

    const int t = threadIdx.x;
    const int lane = t & 63, wave = t >> 6;
    const int wm = (wave >> 1) << 6, wn = (wave & 1) << 6;
    const int fr = lane & 15, quad = lane >> 4;
    float* ws = (float*)As + wave * 16 * EP_LD;   // wave-private (post-barrier)
    const int rrow = lane >> 2;
    const int cseg = (lane & 3) << 4;
    #pragma unroll
    for (int mi = 0; mi < 4; mi++) {
        #pragma unroll
        for (int ni = 0; ni < 4; ni++)
            #pragma unroll
            for (int reg = 0; reg < 4; reg++)
                ws[(quad * 4 + reg) * EP_LD + ni * 16 + fr] = acc[mi][ni][reg];
        int gr = m0 + wm + mi * 16 + rrow;
        if (gr >= M) continue;
        int gc = n0 + wn + cseg;
        float vals[16];
        #pragma unroll
        for (int j = 0; j < 16; j++) {
            float v = ws[rrow * EP_LD + cseg + j] + bias[gc + j];
            if (act == 1) v = (v >= 0.f) ? v : 0.01f * v;
            vals[j] = v;
        }
        if (C) {
            float* cp = C + (size_t)gr * ldc + gc;
            #pragma unroll
            for (int j4 = 0; j4 < 4; j4++)
                *(float4*)(cp + j4 * 4) = make_float4(vals[j4 * 4], vals[j4 * 4 + 1],
                                                      vals[j4 * 4 + 2], vals[j4 * 4 + 3]);
        }
        if (Cbf) {
            unsigned pk[8];
            #pragma unroll
            for (int j2 = 0; j2 < 8; j2++)
                pk[j2] = ((unsigned)f2bf(vals[2 * j2 + 1]) << 16) | (unsigned)f2bf(vals[2 * j2]);
            unsigned* bp = (unsigned*)(Cbf + (size_t)gr * ldcbf + gc);
            *(uint4*)bp       = make_uint4(pk[0], pk[1], pk[2], pk[3]);
            *(uint4*)(bp + 4) = make_uint4(pk[4], pk[5], pk[6], pk[7]);
        }
    }
}

// ---------------------------------------------------------------------------
// v6 projection: qhat only (= h@G + c, scaled; 3 rel x 512). Wt4: [1536][128].
//   bx (0..11): -> qhat3[r=bx/4][gr][(bx%4)*128+..]
// ---------------------------------------------------------------------------
__global__ __launch_bounds__(256) void gemm_qkvs_v4(
    const short* __restrict__ A,       // h_bf [N,128]
    const short* __restrict__ Wt, const float* __restrict__ bias,
    short* __restrict__ qhat3, int M)
{
    __shared__ short As[128 * SAP];
    __shared__ short Bs[128 * SAP];
    f32x4 acc[4][4];
    #pragma unroll
    for (int i = 0; i < 4; i++)
        #pragma unroll
        for (int j = 0; j < 4; j++) acc[i][j] = (f32x4){0.f, 0.f, 0.f, 0.f};
    int m0 = blockIdx.y * 128, bx = blockIdx.x, n0 = bx * 128;
    mfma_core(A, 128, A, 128, KBIG, Wt, M, 128, m0, n0, As, Bs, acc);

    const int t = threadIdx.x;
    const int lane = t & 63, wave = t >> 6;
    const int wm = (wave >> 1) << 6, wn = (wave & 1) << 6;
    const int fr = lane & 15, quad = lane >> 4;
    float* ws = (float*)As + wave * 16 * EP_LD;
    const int rrow = lane >> 2;
    const int cseg = (lane & 3) << 4;
    const int r = bx >> 2;
    #pragma unroll
    for (int mi = 0; mi < 4; mi++) {
        #pragma unroll
        for (int ni = 0; ni < 4; ni++)
            #pragma unroll
            for (int reg = 0; reg < 4; reg++)
                ws[(quad * 4 + reg) * EP_LD + ni * 16 + fr] = acc[mi][ni][reg];
        int gr = m0 + wm + mi * 16 + rrow;
        if (gr >= M) continue;
        int lc = wn + cseg;               // 0..112 local col start
        float vals[16];
        #pragma unroll
        for (int j = 0; j < 16; j++)
            vals[j] = ws[rrow * EP_LD + cseg + j] + bias[n0 + lc + j];
        unsigned pk[8];
        #pragma unroll
        for (int j2 = 0; j2 < 8; j2++)
            pk[j2] = ((unsigned)f2bf(vals[2 * j2 + 1]) << 16) | (unsigned)f2bf(vals[2 * j2]);
        unsigned* bp = (unsigned*)(qhat3 + ((size_t)(r * Nn + gr)) * 512 + (bx - r * 4) * 128 + lc);
        *(uint4*)bp       = make_uint4(pk[0], pk[1], pk[2], pk[3]);
        *(uint4*)(bp + 4) = make_uint4(pk[4], pk[5], pk[6], pk[7]);
    }
}

// ---------------------------------------------------------------------------
// v4 attention: per (dst,rel) wave. logit[h] = qhat[dst,h*128:].h[src] (scale
// folded into qhat). Online softmax per 16-lane head group; accumulate
// Ah[h][128] = sum alpha*h[src]. Writes Ah3 [3][N][512] bf16.
// ---------------------------------------------------------------------------
__global__ __launch_bounds__(256) void attn_v4(
    const short* __restrict__ qhat3, const short* __restrict__ hbf,
    const int* __restrict__ rowptr3, const int* __restrict__ col3,
    short* __restrict__ Ah3)
{
    int wid = ((blockIdx.x * blockDim.x + threadIdx.x) >> 6);
    int lane = threadIdx.x & 63;
    if (wid >= 3 * Nn) return;
    int r = wid / Nn, n = wid - r * Nn;
    const int* rowptr = rowptr3 + r * (Nn + 1);
    const int* colb = col3 + r * EE;
    int beg = rowptr[n], end = rowptr[n + 1];

    uint4 qv = ((const uint4*)(qhat3 + ((size_t)r * Nn + n) * 512))[lane];
    float qf[8];
    unpack8(qv, qf);
    const int l16 = lane & 15;

    float m = -INFINITY, s = 0.f;
    float acc[8] = {0.f, 0.f, 0.f, 0.f, 0.f, 0.f, 0.f, 0.f};

    for (int i = beg; i < end; i++) {
        int src = colb[i];
        uint4 hv = ((const uint4*)(hbf + (size_t)src * 128))[l16];
        float hf[8];
        unpack8(hv, hf);
        float p = qf[0] * hf[0] + qf[1] * hf[1] + qf[2] * hf[2] + qf[3] * hf[3]
                + qf[4] * hf[4] + qf[5] * hf[5] + qf[6] * hf[6] + qf[7] * hf[7];
        p += __shfl_xor(p, 1);
        p += __shfl_xor(p, 2);
        p += __shfl_xor(p, 4);
        p += __shfl_xor(p, 8);
        float nm = fmaxf(m, p);
        float sc = __expf(m - nm);
        float pe = __expf(p - nm);
        s = s * sc + pe;
        #pragma unroll
        for (int j = 0; j < 8; j++) acc[j] = acc[j] * sc + pe * hf[j];
        m = nm;
    }

    float inv = (s > 0.f) ? 1.f / s : 0.f;
    #pragma unroll
    for (int j = 0; j < 8; j++) acc[j] *= inv;

    unsigned p0 = ((unsigned)f2bf(acc[1]) << 16) | (unsigned)f2bf(acc[0]);
    unsigned p1 = ((unsigned)f2bf(acc[3]) << 16) | (unsigned)f2bf(acc[2]);
    unsigned p2 = ((unsigned)f2bf(acc[5]) << 16) | (unsigned)f2bf(acc[4]);
    unsigned p3 = ((unsigned)f2bf(acc[7]) << 16) | (unsigned)f2bf(acc[6]);
    *(uint4*)(Ah3 + ((size_t)r * Nn + n) * 512 + lane * 8) = make_uint4(p0, p1, p2, p3);
}

// ---------------------------------------------------------------------------
// v6 fused U+gate: per (tile, r) block.
//   Phase 1: U = [Ah | h] @ w640t^T  (K = 512+128 via mfma_core ksplit)
//            + bs + mask*bvmean  -> bf16 U-tile in LDS [128][UTS].
//   Phase 2: gate GEMM K=256: A = U-tile (LDS) | h_bf (global), B = gWt (L2).
//   Epilogue: z = sigmoid(g + gb); Hm = tanh(U)*z + h*(1-z)  (fp32 + bf16).
// U_bf never materializes in HBM. Numerics identical to split ufin+gate.
// ---------------------------------------------------------------------------
__global__ __launch_bounds__(256) void ugate_mfma(
    const short* __restrict__ Ah3, const short* __restrict__ w640t,
    const float* __restrict__ bs, const float* __restrict__ bvmean,
    const int* __restrict__ rowptr3,
    const short* __restrict__ gWt, const float* __restrict__ gb,
    const short* __restrict__ Hbf, const float* __restrict__ Hf,
    float* __restrict__ Hm, short* __restrict__ HmBf, int M)
{
    __shared__ short LDSb[2 * 128 * SAP];     // As | Bs, reused as U-tile
    short* As = LDSb;
    short* Bs = LDSb + 128 * SAP;
    f32x4 acc[4][4];
    #pragma unroll
    for (int i = 0; i < 4; i++)
        #pragma unroll
        for (int j = 0; j < 4; j++) acc[i][j] = (f32x4){0.f, 0.f, 0.f, 0.f};
    const int r = blockIdx.z;
    const int m0 = blockIdx.y * 128;
    mfma_core(Ah3 + (size_t)r * Nn * 512, 512, Hbf, 128, 512,
              w640t + (size_t)r * 81920, M, 640, m0, 0, As, Bs, acc);

    const int t = threadIdx.x;
    const int lane = t & 63, wave = t >> 6;
    const int wm = (wave >> 1) << 6, wn = (wave & 1) << 6;
    const int fr = lane & 15, quad = lane >> 4;
    short* Ut = LDSb;                          // [128][UTS] bf16 (34.8 KB <= 36.9 KB)
    const int rp = r * (Nn + 1);

    // phase 1: acc -> U bf16 tile in LDS (mask/bias applied)
    #pragma unroll
    for (int mi = 0; mi < 4; mi++) {
        #pragma unroll
        for (int reg = 0; reg < 4; reg++) {
            int row = wm + mi * 16 + quad * 4 + reg;
            int gr = m0 + row;
            float mk = 0.f;
            if (gr < M) mk = (rowptr3[rp + gr + 1] > rowptr3[rp + gr]) ? 1.f : 0.f;
            #pragma unroll
            for (int ni = 0; ni < 4; ni++) {
                int col = wn + ni * 16 + fr;
                float u = acc[mi][ni][reg] + bs[r * 128 + col] + mk * bvmean[r * 128 + col];
                Ut[row * UTS + col] = (short)f2bf(u);
            }
        }
    }
    __syncthreads();

    // phase 2: gate GEMM, K=256 (U from LDS, h from global, B from L2)
    f32x4 gacc[4][4];
    #pragma unroll
    for (int i = 0; i < 4; i++)
        #pragma unroll
        for (int j = 0; j < 4; j++) gacc[i][j] = (f32x4){0.f, 0.f, 0.f, 0.f};
    #pragma unroll
    for (int kc = 0; kc < 8; kc++) {
        bf16x8 af[4], bfr[4];
        #pragma unroll
        for (int mi = 0; mi < 4; mi++) {
            int row = wm + mi * 16 + fr;
            if (kc < 4) {
                af[mi] = *(const bf16x8*)(Ut + row * UTS + kc * 32 + quad * 8);
            } else {
                int gr = m0 + row;
                bf16x8 v = {0, 0, 0, 0, 0, 0, 0, 0};
                if (gr < M) v = *(const bf16x8*)(Hbf + (size_t)gr * 128 + (kc - 4) * 32 + quad * 8);
                af[mi] = v;
            }
        }
        #pragma unroll
        for (int ni = 0; ni < 4; ni++)
            bfr[ni] = *(const bf16x8*)(gWt + (size_t)(wn + ni * 16 + fr) * 256 + kc * 32 + quad * 8);
        #pragma unroll
        for (int mi = 0; mi < 4; mi++)
            #pragma unroll
            for (int ni = 0; ni < 4; ni++)
                gacc[mi][ni] = __builtin_amdgcn_mfma_f32_16x16x32_bf16(
                    af[mi], bfr[ni], gacc[mi][ni], 0, 0, 0);
    }

    // epilogue: sigmoid/tanh combine -> Hm (fp32) + HmBf (bf16)
    #pragma unroll
    for (int mi = 0; mi < 4; mi++) {
        #pragma unroll
        for (int reg = 0; reg < 4; reg++) {
            int row = wm + mi * 16 + quad * 4 + reg;
            int gr = m0 + row;
            if (gr >= M) continue;
            #pragma unroll
            for (int ni = 0; ni < 4; ni++) {
                int gc = wn + ni * 16 + fr;
                float g = gacc[mi][ni][reg] + gb[gc];
                float z = 1.f / (1.f + __expf(-g));
                float uvv = bf2f(Ut[row * UTS + gc]);
                float hvv = Hf[(size_t)gr * 128 + gc];
                float val = fast_tanh(uvv) * z + hvv * (1.f - z);
                Hm[(size_t)gr * 384 + r * 128 + gc] = val;
                HmBf[(size_t)gr * 384 + r * 128 + gc] = (short)f2bf(val);
            }
        }
    }
}

// Semantic partial sums (no atomics).
__global__ __launch_bounds__(256) void semantic_mfma(
    const short* __restrict__ HmBf, const short* __restrict__ sW1t,
    const float* __restrict__ sb1, const float* __restrict__ sw2,
    float* __restrict__ partial, int M)
{
    __shared__ short As[128 * SAP];
    __shared__ short Bs[128 * SAP];
    __shared__ float red4[4];
    f32x4 acc[4][4];
    #pragma unroll
    for (int i = 0; i < 4; i++)
        #pragma unroll
        for (int j = 0; j < 4; j++) acc[i][j] = (f32x4){0.f, 0.f, 0.f, 0.f};
    int head = blockIdx.x, r = blockIdx.z;
    int m0 = blockIdx.y * 128, n0 = head * 128;
    mfma_core(HmBf + r * 128, 384, HmBf + r * 128, 384, KBIG, sW1t, M, 128, m0, n0, As, Bs, acc);
    const int t = threadIdx.x;
    const int lane = t & 63, wave = t >> 6;
    const int wm = (wave >> 1) << 6, wn = (wave & 1) << 6;
    const int fr = lane & 15, quad = lane >> 4;
    float local = 0.f;
    #pragma unroll
    for (int ni = 0; ni < 4; ni++) {
        int gc = n0 + wn + ni * 16 + fr;
        float b = sb1[gc], w2 = sw2[gc];
        #pragma unroll
        for (int mi = 0; mi < 4; mi++) {
            #pragma unroll
            for (int reg = 0; reg < 4; reg++) {
                int gr = m0 + wm + mi * 16 + quad * 4 + reg;
                if (gr >= M) continue;
                local += fast_tanh(acc[mi][ni][reg] + b) * w2;
            }
        }
    }
    #pragma unroll
    for (int off = 1; off < 64; off <<= 1) local += __shfl_xor(local, off);
    if (lane == 0) red4[wave] = local;
    __syncthreads();
    if (t == 0)
        partial[(head * 3 + r) * MT_M + blockIdx.y] = red4[0] + red4[1] + red4[2] + red4[3];
}

__global__ void reduce12_kernel(const float* __restrict__ partial, float* __restrict__ scores)
{
    int z = blockIdx.x;
    int lane = threadIdx.x;   // 64 threads
    float s = 0.f;
    for (int i = lane; i < MT_M; i += 64) s += partial[z * MT_M + i];
    #pragma unroll
    for (int off = 1; off < 64; off <<= 1) s += __shfl_xor(s, off);
    if (lane == 0) scores[z] = s;
}

__global__ void compute_w_kernel(const float* __restrict__ scores, float* __restrict__ w, float invN)
{
    if (blockIdx.x == 0 && threadIdx.x == 0) {
        float wr[3] = {0.f, 0.f, 0.f};
        for (int h = 0; h < 4; h++) {
            float s0 = scores[h * 3 + 0] * invN;
            float s1 = scores[h * 3 + 1] * invN;
            float s2 = scores[h * 3 + 2] * invN;
            float mx = fmaxf(s0, fmaxf(s1, s2));
            float e0 = __expf(s0 - mx), e1 = __expf(s1 - mx), e2 = __expf(s2 - mx);
            float inv = 1.f / (e0 + e1 + e2);
            wr[0] += 0.25f * e0 * inv;
            wr[1] += 0.25f * e1 * inv;
            wr[2] += 0.25f * e2 * inv;
        }
        w[0] = wr[0]; w[1] = wr[1]; w[2] = wr[2];
    }
}

__global__ void mix_kernel(const float* __restrict__ Hm, const float* __restrict__ w,
                           float* __restrict__ h, short* __restrict__ hbf, int total4)
{
    int i = blockIdx.x * blockDim.x + threadIdx.x;
    if (i >= total4) return;
    int n = i >> 5, c4 = (i & 31) << 2;
    const float* row = Hm + (size_t)n * 384 + c4;
    float4 a = *(const float4*)row;
    float4 b = *(const float4*)(row + 128);
    float4 c = *(const float4*)(row + 256);
    float w0 = w[0], w1 = w[1], w2 = w[2];
    float4 v = make_float4(w0 * a.x + w1 * b.x + w2 * c.x,
                           w0 * a.y + w1 * b.y + w2 * c.y,
                           w0 * a.z + w1 * b.z + w2 * c.z,
                           w0 * a.w + w1 * b.w + w2 * c.w);
    *(float4*)(h + (size_t)n * 128 + c4) = v;
    unsigned p0 = ((unsigned)f2bf(v.y) << 16) | (unsigned)f2bf(v.x);
    unsigned p1 = ((unsigned)f2bf(v.w) << 16) | (unsigned)f2bf(v.z);
    *(uint2*)(hbf + (size_t)n * 128 + c4) = make_uint2(p0, p1);
}

// --------------------------- conversions -----------------------------------
__global__ void convert_bf16_kernel(const float* __restrict__ src, unsigned* __restrict__ dst, int n_pairs)
{
    int i = blockIdx.x * blockDim.x + threadIdx.x;
    if (i >= n_pairs) return;
    float2 f = ((const float2*)src)[i];
    dst[i] = ((unsigned)f2bf(f.y) << 16) | (unsigned)f2bf(f.x);
}

__global__ void prep_global_kernel(const float* __restrict__ lin1_W, const float* __restrict__ lin2_W,
                                   short* __restrict__ lin1Wt, short* __restrict__ lin2Wt)
{
    int id = blockIdx.x * blockDim.x + threadIdx.x;
    if (id < 98304) {
        int n = id / 768, k = id % 768;
        lin1Wt[id] = (short)f2bf(lin1_W[k * 128 + n]);
    } else if (id < 114688) {
        int r = id - 98304;
        int n = r / 128, k = r % 128;
        lin2Wt[r] = (short)f2bf(lin2_W[k * 128 + n]);
    }
}

// v6 per-layer prep: gWt [128][256], sW1t [512][128],
// w640t [3][128][640] (cols: k<512 -> 0.25*Wv remap, k>=512 -> Ws), bvmean.
__global__ void prep_layer_v6(
    const float* __restrict__ Ws, const float* __restrict__ gW,
    const float* __restrict__ sW1, const float* __restrict__ Wv,
    const float* __restrict__ bv,
    short* __restrict__ gWt, short* __restrict__ sW1t,
    short* __restrict__ w640t, float* __restrict__ bvmean)
{
    const int S0 = 32768;              // gWt
    const int S1 = S0 + 65536;         // sW1t
    const int S2 = S1 + 245760;        // w640t [3][128][640]
    const int S3 = S2 + 384;           // bvmean
    int id = blockIdx.x * blockDim.x + threadIdx.x;
    if (id < S0) {
        int n = id / 256, k = id - n * 256;
        gWt[id] = (short)f2bf(gW[k * 128 + n]);
    } else if (id < S1) {
        int q = id - S0;
        int h = q / 16384, rem = q - h * 16384;
        int n = rem / 128, k = rem - n * 128;
        sW1t[q] = (short)f2bf(sW1[(size_t)h * 16384 + k * 128 + n]);
    } else if (id < S2) {
        int q = id - S1;
        int r = q / 81920, rem = q - r * 81920;
        int d = rem / 640, k = rem - d * 640;
        float v;
        if (k < 512) {
            int hh = k >> 7, j = k & 127;
            v = 0.25f * Wv[(size_t)r * 65536 + j * 512 + hh * 128 + d];
        } else {
            v = Ws[(size_t)r * 16384 + (k - 512) * 128 + d];
        }
        w640t[q] = (short)f2bf(v);
    } else if (id < S3) {
        int q = id - S2;           // r*128 + d
        int r = q >> 7, d = q & 127;
        bvmean[q] = 0.25f * (bv[r * 512 + d] + bv[r * 512 + 128 + d]
                           + bv[r * 512 + 256 + d] + bv[r * 512 + 384 + d]);
    }
}

// ---------------------------------------------------------------------------
// G precompute v2: parallel + bank-safe. Grid (8 jg, 4 h, 6 lz) = 192 blocks.
// Writes G rows r*512+h*128+j of Wt4 [1536][128] and bias c[j].
// ---------------------------------------------------------------------------
__global__ __launch_bounds__(256) void gmat_v2(
    const float* __restrict__ Wq0, const float* __restrict__ Wk0, const float* __restrict__ bq0,
    const float* __restrict__ Wq1, const float* __restrict__ Wk1, const float* __restrict__ bq1,
    short* __restrict__ Wt4, float* __restrict__ B4)
{
    __shared__ float WqL[128 * 129];   // [i][d], pad 129 -> lane-i reads 2-way
    __shared__ float WkL[16 * 128];    // [jl][d], broadcast reads
    const int jg = blockIdx.x;         // 0..7 (16 j's each)
    const int h  = blockIdx.y;         // 0..3
    const int lz = blockIdx.z;         // 0..5
    const int l = lz / 3, r = lz - l * 3;
    const float* Wq = l ? Wq1 : Wq0;
    const float* Wk = l ? Wk1 : Wk0;
    const float* bq = l ? bq1 : bq0;
    short* Wt = Wt4 + (size_t)l * 196608;
    float* Bb = B4 + l * 1536;
    const float scale = 0.088388347648318447f;   // 1/sqrt(128)
    const int t = threadIdx.x;

    for (int v = t; v < 4096; v += 256) {
        int i = v >> 5, d4 = (v & 31) << 2;
        float4 q = *(const float4*)(Wq + (size_t)r * 65536 + i * 512 + h * 128 + d4);
        float* wp = WqL + i * 129 + d4;
        wp[0] = q.x; wp[1] = q.y; wp[2] = q.z; wp[3] = q.w;
    }
    for (int v = t; v < 512; v += 256) {
        int jl = v >> 5, d4 = (v & 31) << 2;
        float4 q = *(const float4*)(Wk + (size_t)r * 65536 + (jg * 16 + jl) * 512 + h * 128 + d4);
        float* wp = WkL + jl * 128 + d4;
        wp[0] = q.x; wp[1] = q.y; wp[2] = q.z; wp[3] = q.w;
    }
    __syncthreads();

    const int i = t & 127;
    const int jh = t >> 7;             // 0/1 (wave-uniform)
    const float* wk = WkL + jh * 8 * 128;
    float acc[8] = {0.f, 0.f, 0.f, 0.f, 0.f, 0.f, 0.f, 0.f};
    #pragma unroll 4
    for (int d = 0; d < 128; d++) {
        float wq = WqL[i * 129 + d];
        #pragma unroll
        for (int jj = 0; jj < 8; jj++)
            acc[jj] += wq * wk[jj * 128 + d];
    }
    short* wrow = Wt + ((size_t)(r * 512 + h * 128 + jg * 16 + jh * 8)) * 128 + i;
    #pragma unroll
    for (int jj = 0; jj < 8; jj++)
        wrow[(size_t)jj * 128] = (short)f2bf(scale * acc[jj]);

    if (t < 16) {
        const float* bqh = bq + r * 512 + h * 128;
        float c = 0.f;
        for (int d = 0; d < 128; d++) c += bqh[d] * WkL[t * 128 + d];
        Bb[r * 512 + h * 128 + jg * 16 + t] = scale * c;
    }
}

// --------------------------- CSR build (once) ------------------------------
__global__ void zero_i32_kernel(int* __restrict__ p, int n)
{
    int i = blockIdx.x * blockDim.x + threadIdx.x;
    if (i < n) p[i] = 0;
}

__global__ void hist3_kernel(const int* __restrict__ edges, int* __restrict__ cnt3)
{
    int i = blockIdx.x * blockDim.x + threadIdx.x;
    if (i >= 3 * EE) return;
    int r = i / EE, e = i - r * EE;
    int d = edges[(size_t)r * 2 * EE + EE + e];
    atomicAdd(&cnt3[r * Nn + d], 1);
}

__global__ __launch_bounds__(1024) void scan3_kernel(const int* __restrict__ cnt3,
                                                     int* __restrict__ rowptr3)
{
    __shared__ int part[1024];
    const int r = blockIdx.x;
    const int* cnt = cnt3 + r * Nn;
    int* rowptr = rowptr3 + r * (Nn + 1);
    int tid = threadIdx.x;
    int per = (Nn + 1023) >> 10;
    int base = tid * per;
    int s = 0;
    for (int i = 0; i < per; i++) {
        int idx = base + i;
        if (idx < Nn) s += cnt[idx];
    }
    part[tid] = s;
    __syncthreads();
    for (int off = 1; off < 1024; off <<= 1) {
        int val = (tid >= off) ? part[tid - off] : 0;
        __syncthreads();
        part[tid] += val;
        __syncthreads();
    }
    int excl = (tid == 0) ? 0 : part[tid - 1];
    for (int i = 0; i < per; i++) {
        int idx = base + i;
        if (idx < Nn) { rowptr[idx] = excl; excl += cnt[idx]; }
    }
    if (tid == 1023) rowptr[Nn] = part[1023];
}

__global__ void scatter3_kernel(const int* __restrict__ edges,
                                const int* __restrict__ rowptr3, int* __restrict__ fill3,
                                int* __restrict__ col3)
{
    int i = blockIdx.x * blockDim.x + threadIdx.x;
    if (i >= 3 * EE) return;
    int r = i / EE, e = i - r * EE;
    int src = edges[(size_t)r * 2 * EE + e];
    int d   = edges[(size_t)r * 2 * EE + EE + e];
    int pos = rowptr3[r * (Nn + 1) + d] + atomicAdd(&fill3[r * Nn + d], 1);
    col3[r * EE + pos] = src;
}

// --------------------------- classifier -----------------------------------
__global__ void clf_kernel(const float* __restrict__ t, const float* __restrict__ W,
                           const float* __restrict__ b, float* __restrict__ out, int M)
{
    int n = blockIdx.x * blockDim.x + threadIdx.x;
    if (n >= M) return;
    const float* row = t + (size_t)n * 128;
    float a0 = b[0], a1 = b[1];
    #pragma unroll
    for (int kk = 0; kk < 128; kk++) {
        float a = row[kk];
        a0 += a * W[kk * 2];
        a1 += a * W[kk * 2 + 1];
    }
    out[n * 2] = a0;
    out[n * 2 + 1] = a1;
}

// ---------------------------------------------------------------------------
extern "C" void kernel_launch(void* const* d_in, const int* in_sizes, int n_in,
                              void* d_out, int out_size, void* d_ws, size_t ws_size,
                              hipStream_t stream)
{
    const float* x      = (const float*)d_in[0];
    const int*   edges  = (const int*)d_in[1];
    const float* lin1_W = (const float*)d_in[2];
    const float* lin1_b = (const float*)d_in[3];
    const int L0 = 4, L1 = 17;
    const float* lin2_W = (const float*)d_in[30];
    const float* lin2_b = (const float*)d_in[31];
    const float* clf_W  = (const float*)d_in[32];
    const float* clf_b  = (const float*)d_in[33];
    float* out = (float*)d_out;

    char* w = (char*)d_ws;
    size_t off = 0;
    auto alloc = [&](size_t bytes) { void* p = w + off; off = (off + bytes + 255) & ~(size_t)255; return p; };
    float* h      = (float*)alloc((size_t)Nn * 128 * 4);     // 15.4 MB
    short* h_bf   = (short*)alloc((size_t)Nn * 128 * 2);     //  7.7 MB
    // BIG union (184.3 MB): qhat3 [3][N][512] + Ah3 [3][N][512] bf16
    //   <-> x_bf [N,768] bf16  <-> Hm [N,384] f32 + Hm_bf [N,384] bf16 <-> lin2o
    const size_t QH = (size_t)3 * Nn * 512 * 2;
    char* BIG     = (char*)alloc(2 * QH);
    short* qhat3  = (short*)BIG;
    short* Ah3    = (short*)(BIG + QH);
    short* x_bf   = (short*)BIG;
    float* Hm     = (float*)BIG;
    short* Hm_bf  = (short*)(BIG + (size_t)Nn * 384 * 4);
    float* lin2o  = (float*)BIG;
    short* lin1Wt = (short*)alloc((size_t)98304 * 2);
    short* lin2Wt = (short*)alloc((size_t)16384 * 2);
    short* qkvsWt4 = (short*)alloc((size_t)2 * 196608 * 2);  // [layer][1536][128] (G)
    short* gWt    = (short*)alloc((size_t)2 * 32768 * 2);
    short* sW1t   = (short*)alloc((size_t)2 * 65536 * 2);
    short* w640t  = (short*)alloc((size_t)2 * 245760 * 2);   // [layer][3][128][640]
    float* qkvsB4 = (float*)alloc((size_t)2 * 1536 * 4);
    float* bvmean = (float*)alloc((size_t)2 * 384 * 4);
    int* rowptr3  = (int*)alloc((size_t)3 * (Nn + 1) * 4);
    int* cnt3     = (int*)alloc((size_t)3 * Nn * 4);
    int* col3     = (int*)alloc((size_t)3 * EE * 4);
    float* partial = (float*)alloc((size_t)12 * MT_M * 4);
    float* scores = (float*)alloc(12 * 4);
    float* wmix   = (float*)alloc(3 * 4);

    const int MT = MT_M;    // 235
    dim3 blk(256);

    // ---- prep ----
    {
        int n_pairs = Nn * 768 / 2;
        convert_bf16_kernel<<<(n_pairs + 255) / 256, blk, 0, stream>>>(x, (unsigned*)x_bf, n_pairs);
        prep_global_kernel<<<(114688 + 255) / 256, blk, 0, stream>>>(lin1_W, lin2_W, lin1Wt, lin2Wt);
        for (int l = 0; l < 2; l++) {
            int base = (l == 0) ? L0 : L1;
            prep_layer_v6<<<(344448 + 255) / 256, blk, 0, stream>>>(
                (const float*)d_in[base + 6], (const float*)d_in[base + 8],
                (const float*)d_in[base + 10], (const float*)d_in[base + 4],
                (const float*)d_in[base + 5],
                gWt + (size_t)l * 32768, sW1t + (size_t)l * 65536,
                w640t + (size_t)l * 245760, bvmean + (size_t)l * 384);
        }
        gmat_v2<<<dim3(8, 4, 6), blk, 0, stream>>>(
            (const float*)d_in[L0 + 0], (const float*)d_in[L0 + 2], (const float*)d_in[L0 + 1],
            (const float*)d_in[L1 + 0], (const float*)d_in[L1 + 2], (const float*)d_in[L1 + 1],
            qkvsWt4, qkvsB4);
        zero_i32_kernel<<<(3 * Nn + 255) / 256, blk, 0, stream>>>(cnt3, 3 * Nn);
        hist3_kernel<<<(3 * EE + 255) / 256, blk, 0, stream>>>(edges, cnt3);
        scan3_kernel<<<3, 1024, 0, stream>>>(cnt3, rowptr3);
        zero_i32_kernel<<<(3 * Nn + 255) / 256, blk, 0, stream>>>(cnt3, 3 * Nn);
        scatter3_kernel<<<(3 * EE + 255) / 256, blk, 0, stream>>>(edges, rowptr3, cnt3, col3);
    }

    // lin1: h = lrelu(x @ lin1_W + b)   (x_bf in BIG; done before qhat overwrites)
    gemm_mfma<<<dim3(1, MT), blk, 0, stream>>>(
        x_bf, 768, x_bf, 768, KBIG, lin1Wt, lin1_b, h, 128, h_bf, 128, Nn, 768, 1);

    for (int l = 0; l < 2; l++) {
        int base = (l == 0) ? L0 : L1;
        const float* bs  = (const float*)d_in[base + 7];
        const float* gb  = (const float*)d_in[base + 9];
        const float* sb1 = (const float*)d_in[base + 11];
        const float* sw2 = (const float*)d_in[base + 12];
        short* lWt4   = qkvsWt4 + (size_t)l * 196608;
        short* lgWt   = gWt + (size_t)l * 32768;
        short* lsW1t  = sW1t + (size_t)l * 65536;
        short* lw640  = w640t + (size_t)l * 245760;
        float* lB4    = qkvsB4 + (size_t)l * 1536;
        float* lbvm   = bvmean + (size_t)l * 384;

        // qhat (3 rel x 512 cols)
        gemm_qkvs_v4<<<dim3(12, MT), blk, 0, stream>>>(
            h_bf, lWt4, lB4, qhat3, Nn);

        // attention in h-space: Ah = sum alpha * h[src]
        attn_v4<<<(3 * Nn + 3) / 4, blk, 0, stream>>>(qhat3, h_bf, rowptr3, col3, Ah3);

        // fused U-finalize + gate -> Hm (fp32 + bf16); U never hits HBM
        ugate_mfma<<<dim3(1, MT, 3), blk, 0, stream>>>(
            Ah3, lw640, bs, lbvm, rowptr3, lgWt, gb, h_bf, h, Hm, Hm_bf, Nn);

        // semantic attention
        semantic_mfma<<<dim3(4, MT, 3), blk, 0, stream>>>(Hm_bf, lsW1t, sb1, sw2, partial, Nn);
        reduce12_kernel<<<12, 64, 0, stream>>>(partial, scores);
        compute_w_kernel<<<1, 64, 0, stream>>>(scores, wmix, 1.f / (float)Nn);
        mix_kernel<<<(Nn * 32 + 255) / 256, blk, 0, stream>>>(Hm, wmix, h, h_bf, Nn * 32);
    }

    // lin2 + lrelu -> lin2o (BIG region, Hm dead after mix)
    gemm_mfma<<<dim3(1, MT), blk, 0, stream>>>(
        h_bf, 128, h_bf, 128, KBIG, lin2Wt, lin2_b, lin2o, 128, (short*)nullptr, 0, Nn, 128, 1);
    clf_kernel<<<(Nn + 255) / 256, blk, 0, stream>>>(lin2o, clf_W, clf_b, out, Nn);
}

// Round 6
// 791.788 us; speedup vs baseline: 1.0486x; 1.0486x over previous
//
#include <hip/hip_runtime.h>
#include <math.h>

#define Nn 30000
#define RR 3
#define EE 80000
#define MT_M 235      // ceil(Nn/128)

#define SAP 72        // padded LDS row stride (bf16 elems) for staged tiles
#define EP_LD 68      // per-wave epilogue scratch stride (floats)
#define KBIG 0x40000000

typedef __attribute__((ext_vector_type(8))) short bf16x8;
typedef __attribute__((ext_vector_type(4))) float f32x4;

__device__ __forceinline__ unsigned short f2bf(float f) {
    union { float f; unsigned u; } v; v.f = f;
    unsigned r = v.u + 0x7fff + ((v.u >> 16) & 1);
    return (unsigned short)(r >> 16);
}
__device__ __forceinline__ float bf2f(short h) {
    union { unsigned u; float f; } v;
    v.u = ((unsigned)(unsigned short)h) << 16;
    return v.f;
}
__device__ __forceinline__ float fast_tanh(float x) {
    float e = __expf(2.f * x);
    return 1.f - 2.f / (e + 1.f);
}
__device__ __forceinline__ void unpack8(uint4 u, float* f) {
    union { unsigned u; float f; } a;
    a.u = u.x << 16;          f[0] = a.f;
    a.u = u.x & 0xffff0000u;  f[1] = a.f;
    a.u = u.y << 16;          f[2] = a.f;
    a.u = u.y & 0xffff0000u;  f[3] = a.f;
    a.u = u.z << 16;          f[4] = a.f;
    a.u = u.z & 0xffff0000u;  f[5] = a.f;
    a.u = u.w << 16;          f[6] = a.f;
    a.u = u.w & 0xffff0000u;  f[7] = a.f;
}

// ---------------------------------------------------------------------------
// LDS-staged MFMA GEMM core (128x128 tile, BK=64, 4 waves x 64x64).
// ---------------------------------------------------------------------------
__device__ __forceinline__ void mfma_core(
    const short* __restrict__ A, int lda,
    const short* __restrict__ A2, int lda2, int ksplit,
    const short* __restrict__ Bt,
    int M, int K, int m0, int n0,
    short* As, short* Bs, f32x4 (&acc)[4][4])
{
    const int t = threadIdx.x;
    const int srow = t >> 3;          // 0..31
    const int scol = (t & 7) << 3;    // 0..56 step 8
    const int lane = t & 63;
    const int wave = t >> 6;
    const int wm = (wave >> 1) << 6;
    const int wn = (wave & 1) << 6;
    const int fr = lane & 15;
    const int quad = lane >> 4;

    for (int k0 = 0; k0 < K; k0 += 64) {
        const short* Abase; int kk0, ldax;
        if (k0 < ksplit) { Abase = A;  kk0 = k0;          ldax = lda;  }
        else             { Abase = A2; kk0 = k0 - ksplit; ldax = lda2; }
        #pragma unroll
        for (int rr = 0; rr < 4; rr++) {
            int r = srow + rr * 32;
            int gr = m0 + r;
            bf16x8 va = {0, 0, 0, 0, 0, 0, 0, 0};
            if (gr < M) va = *(const bf16x8*)(Abase + (size_t)gr * ldax + kk0 + scol);
            *(bf16x8*)(As + r * SAP + scol) = va;
        }
        #pragma unroll
        for (int rr = 0; rr < 4; rr++) {
            int r = srow + rr * 32;
            bf16x8 vb = *(const bf16x8*)(Bt + (size_t)(n0 + r) * K + k0 + scol);
            *(bf16x8*)(Bs + r * SAP + scol) = vb;
        }
        __syncthreads();
        #pragma unroll
        for (int kc = 0; kc < 2; kc++) {
            bf16x8 af[4], bfr[4];
            #pragma unroll
            for (int i = 0; i < 4; i++)
                af[i] = *(const bf16x8*)(As + (wm + i * 16 + fr) * SAP + kc * 32 + quad * 8);
            #pragma unroll
            for (int i = 0; i < 4; i++)
                bfr[i] = *(const bf16x8*)(Bs + (wn + i * 16 + fr) * SAP + kc * 32 + quad * 8);
            #pragma unroll
            for (int mi = 0; mi < 4; mi++)
                #pragma unroll
                for (int ni = 0; ni < 4; ni++)
                    acc[mi][ni] = __builtin_amdgcn_mfma_f32_16x16x32_bf16(
                        af[mi], bfr[ni], acc[mi][ni], 0, 0, 0);
        }
        __syncthreads();
    }
}

// General GEMM: C = act(A @ Bt^T + bias). Wave-private LDS repack epilogue.
__global__ __launch_bounds__(256) void gemm_mfma(
    const short* __restrict__ A, int lda,
    const short* __restrict__ A2, int lda2, int ksplit,
    const short* __restrict__ Bt, const float* __restrict__ bias,
    float* __restrict__ C, int ldc, short* __restrict__ Cbf, int ldcbf,
    int M, int K, int act)
{
    __shared__ short As[128 * SAP];
    __shared__ short Bs[128 * SAP];
    f32x4 acc[4][4];
    #pragma unroll
    for (int i = 0; i < 4; i++)
        #pragma unroll
        for (int j = 0; j < 4; j++) acc[i][j] = (f32x4){0.f, 0.f, 0.f, 0.f};
    int m0 = blockIdx.y * 128, n0 = blockIdx.x * 128;
    mfma_core(A, lda, A2, lda2, ksplit, Bt, M, K, m0, n0, As, Bs, acc);

    const int t = threadIdx.x;
    const int lane = t & 63, wave = t >> 6;
    const int wm = (wave >> 1) << 6, wn = (wave & 1) << 6;
    const int fr = lane & 15, quad = lane >> 4;
    float* ws = (float*)As + wave * 16 * EP_LD;   // wave-private (post-barrier)
    const int rrow = lane >> 2;
    const int cseg = (lane & 3) << 4;
    #pragma unroll
    for (int mi = 0; mi < 4; mi++) {
        #pragma unroll
        for (int ni = 0; ni < 4; ni++)
            #pragma unroll
            for (int reg = 0; reg < 4; reg++)
                ws[(quad * 4 + reg) * EP_LD + ni * 16 + fr] = acc[mi][ni][reg];
        int gr = m0 + wm + mi * 16 + rrow;
        if (gr >= M) continue;
        int gc = n0 + wn + cseg;
        float vals[16];
        #pragma unroll
        for (int j = 0; j < 16; j++) {
            float v = ws[rrow * EP_LD + cseg + j] + bias[gc + j];
            if (act == 1) v = (v >= 0.f) ? v : 0.01f * v;
            vals[j] = v;
        }
        if (C) {
            float* cp = C + (size_t)gr * ldc + gc;
            #pragma unroll
            for (int j4 = 0; j4 < 4; j4++)
                *(float4*)(cp + j4 * 4) = make_float4(vals[j4 * 4], vals[j4 * 4 + 1],
                                                      vals[j4 * 4 + 2], vals[j4 * 4 + 3]);
        }
        if (Cbf) {
            unsigned pk[8];
            #pragma unroll
            for (int j2 = 0; j2 < 8; j2++)
                pk[j2] = ((unsigned)f2bf(vals[2 * j2 + 1]) << 16) | (unsigned)f2bf(vals[2 * j2]);
            unsigned* bp = (unsigned*)(Cbf + (size_t)gr * ldcbf + gc);
            *(uint4*)bp       = make_uint4(pk[0], pk[1], pk[2], pk[3]);
            *(uint4*)(bp + 4) = make_uint4(pk[4], pk[5], pk[6], pk[7]);
        }
    }
}

// ---------------------------------------------------------------------------
// v6 projection: qhat only (= h@G + c, scaled; 3 rel x 512). Wt4: [1536][128].
//   bx (0..11): -> qhat3[r=bx/4][gr][(bx%4)*128+..]
// ---------------------------------------------------------------------------
__global__ __launch_bounds__(256) void gemm_qkvs_v4(
    const short* __restrict__ A,       // h_bf [N,128]
    const short* __restrict__ Wt, const float* __restrict__ bias,
    short* __restrict__ qhat3, int M)
{
    __shared__ short As[128 * SAP];
    __shared__ short Bs[128 * SAP];
    f32x4 acc[4][4];
    #pragma unroll
    for (int i = 0; i < 4; i++)
        #pragma unroll
        for (int j = 0; j < 4; j++) acc[i][j] = (f32x4){0.f, 0.f, 0.f, 0.f};
    int m0 = blockIdx.y * 128, bx = blockIdx.x, n0 = bx * 128;
    mfma_core(A, 128, A, 128, KBIG, Wt, M, 128, m0, n0, As, Bs, acc);

    const int t = threadIdx.x;
    const int lane = t & 63, wave = t >> 6;
    const int wm = (wave >> 1) << 6, wn = (wave & 1) << 6;
    const int fr = lane & 15, quad = lane >> 4;
    float* ws = (float*)As + wave * 16 * EP_LD;
    const int rrow = lane >> 2;
    const int cseg = (lane & 3) << 4;
    const int r = bx >> 2;
    #pragma unroll
    for (int mi = 0; mi < 4; mi++) {
        #pragma unroll
        for (int ni = 0; ni < 4; ni++)
            #pragma unroll
            for (int reg = 0; reg < 4; reg++)
                ws[(quad * 4 + reg) * EP_LD + ni * 16 + fr] = acc[mi][ni][reg];
        int gr = m0 + wm + mi * 16 + rrow;
        if (gr >= M) continue;
        int lc = wn + cseg;               // 0..112 local col start
        float vals[16];
        #pragma unroll
        for (int j = 0; j < 16; j++)
            vals[j] = ws[rrow * EP_LD + cseg + j] + bias[n0 + lc + j];
        unsigned pk[8];
        #pragma unroll
        for (int j2 = 0; j2 < 8; j2++)
            pk[j2] = ((unsigned)f2bf(vals[2 * j2 + 1]) << 16) | (unsigned)f2bf(vals[2 * j2]);
        unsigned* bp = (unsigned*)(qhat3 + ((size_t)(r * Nn + gr)) * 512 + (bx - r * 4) * 128 + lc);
        *(uint4*)bp       = make_uint4(pk[0], pk[1], pk[2], pk[3]);
        *(uint4*)(bp + 4) = make_uint4(pk[4], pk[5], pk[6], pk[7]);
    }
}

// ---------------------------------------------------------------------------
// v4 attention (+ 2-deep gather prefetch): per (dst,rel) wave.
// logit[h] = qhat[dst,h*128:].h[src]; online softmax per 16-lane head group;
// Ah[h][128] = sum alpha*h[src]. Writes Ah3 [3][N][512] bf16.
// ---------------------------------------------------------------------------
__global__ __launch_bounds__(256) void attn_v4(
    const short* __restrict__ qhat3, const short* __restrict__ hbf,
    const int* __restrict__ rowptr3, const int* __restrict__ col3,
    short* __restrict__ Ah3)
{
    int wid = ((blockIdx.x * blockDim.x + threadIdx.x) >> 6);
    int lane = threadIdx.x & 63;
    if (wid >= 3 * Nn) return;
    int r = wid / Nn, n = wid - r * Nn;
    const int* rowptr = rowptr3 + r * (Nn + 1);
    const int* colb = col3 + r * EE;
    int beg = rowptr[n], end = rowptr[n + 1];

    uint4 qv = ((const uint4*)(qhat3 + ((size_t)r * Nn + n) * 512))[lane];
    float qf[8];
    unpack8(qv, qf);
    const int l16 = lane & 15;

    float m = -INFINITY, s = 0.f;
    float acc[8] = {0.f, 0.f, 0.f, 0.f, 0.f, 0.f, 0.f, 0.f};

    uint4 hv_n = make_uint4(0, 0, 0, 0);
    if (beg < end)
        hv_n = ((const uint4*)(hbf + (size_t)colb[beg] * 128))[l16];
    for (int i = beg; i < end; i++) {
        uint4 hv = hv_n;
        if (i + 1 < end)
            hv_n = ((const uint4*)(hbf + (size_t)colb[i + 1] * 128))[l16];
        float hf[8];
        unpack8(hv, hf);
        float p = qf[0] * hf[0] + qf[1] * hf[1] + qf[2] * hf[2] + qf[3] * hf[3]
                + qf[4] * hf[4] + qf[5] * hf[5] + qf[6] * hf[6] + qf[7] * hf[7];
        p += __shfl_xor(p, 1);
        p += __shfl_xor(p, 2);
        p += __shfl_xor(p, 4);
        p += __shfl_xor(p, 8);
        float nm = fmaxf(m, p);
        float sc = __expf(m - nm);
        float pe = __expf(p - nm);
        s = s * sc + pe;
        #pragma unroll
        for (int j = 0; j < 8; j++) acc[j] = acc[j] * sc + pe * hf[j];
        m = nm;
    }

    float inv = (s > 0.f) ? 1.f / s : 0.f;
    #pragma unroll
    for (int j = 0; j < 8; j++) acc[j] *= inv;

    unsigned p0 = ((unsigned)f2bf(acc[1]) << 16) | (unsigned)f2bf(acc[0]);
    unsigned p1 = ((unsigned)f2bf(acc[3]) << 16) | (unsigned)f2bf(acc[2]);
    unsigned p2 = ((unsigned)f2bf(acc[5]) << 16) | (unsigned)f2bf(acc[4]);
    unsigned p3 = ((unsigned)f2bf(acc[7]) << 16) | (unsigned)f2bf(acc[6]);
    *(uint4*)(Ah3 + ((size_t)r * Nn + n) * 512 + lane * 8) = make_uint4(p0, p1, p2, p3);
}

// ---------------------------------------------------------------------------
// v7 U finalize: U_bf = [Ah | h] @ w640t^T + bs + mask*bvmean.  K = 512+128.
// (h@Ws folded into the K-split; no U-init write in qkvs, no U read here.)
// ---------------------------------------------------------------------------
__global__ __launch_bounds__(256) void ufin_mfma(
    const short* __restrict__ Ah3, const short* __restrict__ Hbf,
    const short* __restrict__ w640t,
    const float* __restrict__ bs, const float* __restrict__ bvmean,
    const int* __restrict__ rowptr3,
    short* __restrict__ U_bf, int M)
{
    __shared__ short As[128 * SAP];
    __shared__ short Bs[128 * SAP];
    f32x4 acc[4][4];
    #pragma unroll
    for (int i = 0; i < 4; i++)
        #pragma unroll
        for (int j = 0; j < 4; j++) acc[i][j] = (f32x4){0.f, 0.f, 0.f, 0.f};
    int r = blockIdx.z;
    int m0 = blockIdx.y * 128;
    mfma_core(Ah3 + (size_t)r * Nn * 512, 512, Hbf, 128, 512,
              w640t + (size_t)r * 81920, M, 640, m0, 0, As, Bs, acc);

    const int t = threadIdx.x;
    const int lane = t & 63, wave = t >> 6;
    const int wm = (wave >> 1) << 6, wn = (wave & 1) << 6;
    const int fr = lane & 15, quad = lane >> 4;
    float* ws = (float*)As + wave * 16 * EP_LD;
    const int rrow = lane >> 2;
    const int cseg = (lane & 3) << 4;
    const int rp = r * (Nn + 1);
    #pragma unroll
    for (int mi = 0; mi < 4; mi++) {
        #pragma unroll
        for (int ni = 0; ni < 4; ni++)
            #pragma unroll
            for (int reg = 0; reg < 4; reg++)
                ws[(quad * 4 + reg) * EP_LD + ni * 16 + fr] = acc[mi][ni][reg];
        int gr = m0 + wm + mi * 16 + rrow;
        if (gr >= M) continue;
        int gc = wn + cseg;
        float mk = (rowptr3[rp + gr + 1] > rowptr3[rp + gr]) ? 1.f : 0.f;
        float vals[16];
        #pragma unroll
        for (int j = 0; j < 16; j++)
            vals[j] = ws[rrow * EP_LD + cseg + j] + bs[r * 128 + gc + j]
                    + mk * bvmean[r * 128 + gc + j];
        unsigned pk[8];
        #pragma unroll
        for (int j2 = 0; j2 < 8; j2++)
            pk[j2] = ((unsigned)f2bf(vals[2 * j2 + 1]) << 16) | (unsigned)f2bf(vals[2 * j2]);
        unsigned* bp = (unsigned*)(U_bf + (size_t)gr * 384 + r * 128 + gc);
        *(uint4*)bp       = make_uint4(pk[0], pk[1], pk[2], pk[3]);
        *(uint4*)(bp + 4) = make_uint4(pk[4], pk[5], pk[6], pk[7]);
    }
}

// Gate (z = relation): Z = sigmoid([U_r|h] @ gW + gb); Hm_r = tanh(U_r)*Z + h*(1-Z).
__global__ __launch_bounds__(256) void gate_mfma(
    const short* __restrict__ Ubf,   // [N,384] bf16
    const short* __restrict__ Hbf,   // [N,128] bf16
    const short* __restrict__ gWt, const float* __restrict__ gb,
    const float* __restrict__ Hf,    // [N,128] fp32
    float* __restrict__ Hm, short* __restrict__ HmBf,   // [N,384]
    int M)
{
    __shared__ short As[128 * SAP];
    __shared__ short Bs[128 * SAP];
    f32x4 acc[4][4];
    #pragma unroll
    for (int i = 0; i < 4; i++)
        #pragma unroll
        for (int j = 0; j < 4; j++) acc[i][j] = (f32x4){0.f, 0.f, 0.f, 0.f};
    int r = blockIdx.z;
    int m0 = blockIdx.y * 128;
    mfma_core(Ubf + r * 128, 384, Hbf, 128, 128, gWt, M, 256, m0, 0, As, Bs, acc);

    const int t = threadIdx.x;
    const int lane = t & 63, wave = t >> 6;
    const int wm = (wave >> 1) << 6, wn = (wave & 1) << 6;
    const int fr = lane & 15, quad = lane >> 4;
    float* ws = (float*)As + wave * 16 * EP_LD;
    const int rrow = lane >> 2;
    const int cseg = (lane & 3) << 4;
    #pragma unroll
    for (int mi = 0; mi < 4; mi++) {
        #pragma unroll
        for (int ni = 0; ni < 4; ni++)
            #pragma unroll
            for (int reg = 0; reg < 4; reg++)
                ws[(quad * 4 + reg) * EP_LD + ni * 16 + fr] = acc[mi][ni][reg];
        int gr = m0 + wm + mi * 16 + rrow;
        if (gr >= M) continue;
        int gc = wn + cseg;
        const short* up = Ubf + (size_t)gr * 384 + r * 128 + gc;
        const float* hp = Hf + (size_t)gr * 128 + gc;
        float uv[16], hv[16];
        uint4 u0 = *(const uint4*)up;
        uint4 u1 = *(const uint4*)(up + 8);
        unpack8(u0, uv); unpack8(u1, uv + 8);
        #pragma unroll
        for (int j4 = 0; j4 < 4; j4++)
            *(float4*)(hv + j4 * 4) = *(const float4*)(hp + j4 * 4);
        float vals[16];
        #pragma unroll
        for (int j = 0; j < 16; j++) {
            float g = ws[rrow * EP_LD + cseg + j] + gb[gc + j];
            float z = 1.f / (1.f + __expf(-g));
            vals[j] = fast_tanh(uv[j]) * z + hv[j] * (1.f - z);
        }
        float* cp = Hm + (size_t)gr * 384 + r * 128 + gc;
        #pragma unroll
        for (int j4 = 0; j4 < 4; j4++)
            *(float4*)(cp + j4 * 4) = make_float4(vals[j4 * 4], vals[j4 * 4 + 1],
                                                  vals[j4 * 4 + 2], vals[j4 * 4 + 3]);
        unsigned pk[8];
        #pragma unroll
        for (int j2 = 0; j2 < 8; j2++)
            pk[j2] = ((unsigned)f2bf(vals[2 * j2 + 1]) << 16) | (unsigned)f2bf(vals[2 * j2]);
        unsigned* bp = (unsigned*)(HmBf + (size_t)gr * 384 + r * 128 + gc);
        *(uint4*)bp       = make_uint4(pk[0], pk[1], pk[2], pk[3]);
        *(uint4*)(bp + 4) = make_uint4(pk[4], pk[5], pk[6], pk[7]);
    }
}

// Semantic partial sums (no atomics).
__global__ __launch_bounds__(256) void semantic_mfma(
    const short* __restrict__ HmBf, const short* __restrict__ sW1t,
    const float* __restrict__ sb1, const float* __restrict__ sw2,
    float* __restrict__ partial, int M)
{
    __shared__ short As[128 * SAP];
    __shared__ short Bs[128 * SAP];
    __shared__ float red4[4];
    f32x4 acc[4][4];
    #pragma unroll
    for (int i = 0; i < 4; i++)
        #pragma unroll
        for (int j = 0; j < 4; j++) acc[i][j] = (f32x4){0.f, 0.f, 0.f, 0.f};
    int head = blockIdx.x, r = blockIdx.z;
    int m0 = blockIdx.y * 128, n0 = head * 128;
    mfma_core(HmBf + r * 128, 384, HmBf + r * 128, 384, KBIG, sW1t, M, 128, m0, n0, As, Bs, acc);
    const int t = threadIdx.x;
    const int lane = t & 63, wave = t >> 6;
    const int wm = (wave >> 1) << 6, wn = (wave & 1) << 6;
    const int fr = lane & 15, quad = lane >> 4;
    float local = 0.f;
    #pragma unroll
    for (int ni = 0; ni < 4; ni++) {
        int gc = n0 + wn + ni * 16 + fr;
        float b = sb1[gc], w2 = sw2[gc];
        #pragma unroll
        for (int mi = 0; mi < 4; mi++) {
            #pragma unroll
            for (int reg = 0; reg < 4; reg++) {
                int gr = m0 + wm + mi * 16 + quad * 4 + reg;
                if (gr >= M) continue;
                local += fast_tanh(acc[mi][ni][reg] + b) * w2;
            }
        }
    }
    #pragma unroll
    for (int off = 1; off < 64; off <<= 1) local += __shfl_xor(local, off);
    if (lane == 0) red4[wave] = local;
    __syncthreads();
    if (t == 0)
        partial[(head * 3 + r) * MT_M + blockIdx.y] = red4[0] + red4[1] + red4[2] + red4[3];
}

__global__ void reduce12_kernel(const float* __restrict__ partial, float* __restrict__ scores)
{
    int z = blockIdx.x;
    int lane = threadIdx.x;   // 64 threads
    float s = 0.f;
    for (int i = lane; i < MT_M; i += 64) s += partial[z * MT_M + i];
    #pragma unroll
    for (int off = 1; off < 64; off <<= 1) s += __shfl_xor(s, off);
    if (lane == 0) scores[z] = s;
}

__global__ void compute_w_kernel(const float* __restrict__ scores, float* __restrict__ w, float invN)
{
    if (blockIdx.x == 0 && threadIdx.x == 0) {
        float wr[3] = {0.f, 0.f, 0.f};
        for (int h = 0; h < 4; h++) {
            float s0 = scores[h * 3 + 0] * invN;
            float s1 = scores[h * 3 + 1] * invN;
            float s2 = scores[h * 3 + 2] * invN;
            float mx = fmaxf(s0, fmaxf(s1, s2));
            float e0 = __expf(s0 - mx), e1 = __expf(s1 - mx), e2 = __expf(s2 - mx);
            float inv = 1.f / (e0 + e1 + e2);
            wr[0] += 0.25f * e0 * inv;
            wr[1] += 0.25f * e1 * inv;
            wr[2] += 0.25f * e2 * inv;
        }
        w[0] = wr[0]; w[1] = wr[1]; w[2] = wr[2];
    }
}

__global__ void mix_kernel(const float* __restrict__ Hm, const float* __restrict__ w,
                           float* __restrict__ h, short* __restrict__ hbf, int total4)
{
    int i = blockIdx.x * blockDim.x + threadIdx.x;
    if (i >= total4) return;
    int n = i >> 5, c4 = (i & 31) << 2;
    const float* row = Hm + (size_t)n * 384 + c4;
    float4 a = *(const float4*)row;
    float4 b = *(const float4*)(row + 128);
    float4 c = *(const float4*)(row + 256);
    float w0 = w[0], w1 = w[1], w2 = w[2];
    float4 v = make_float4(w0 * a.x + w1 * b.x + w2 * c.x,
                           w0 * a.y + w1 * b.y + w2 * c.y,
                           w0 * a.z + w1 * b.z + w2 * c.z,
                           w0 * a.w + w1 * b.w + w2 * c.w);
    *(float4*)(h + (size_t)n * 128 + c4) = v;
    unsigned p0 = ((unsigned)f2bf(v.y) << 16) | (unsigned)f2bf(v.x);
    unsigned p1 = ((unsigned)f2bf(v.w) << 16) | (unsigned)f2bf(v.z);
    *(uint2*)(hbf + (size_t)n * 128 + c4) = make_uint2(p0, p1);
}

// --------------------------- conversions -----------------------------------
__global__ void convert_bf16_kernel(const float* __restrict__ src, unsigned* __restrict__ dst, int n_pairs)
{
    int i = blockIdx.x * blockDim.x + threadIdx.x;
    if (i >= n_pairs) return;
    float2 f = ((const float2*)src)[i];
    dst[i] = ((unsigned)f2bf(f.y) << 16) | (unsigned)f2bf(f.x);
}

__global__ void prep_global_kernel(const float* __restrict__ lin1_W, const float* __restrict__ lin2_W,
                                   short* __restrict__ lin1Wt, short* __restrict__ lin2Wt)
{
    int id = blockIdx.x * blockDim.x + threadIdx.x;
    if (id < 98304) {
        int n = id / 768, k = id % 768;
        lin1Wt[id] = (short)f2bf(lin1_W[k * 128 + n]);
    } else if (id < 114688) {
        int r = id - 98304;
        int n = r / 128, k = r % 128;
        lin2Wt[r] = (short)f2bf(lin2_W[k * 128 + n]);
    }
}

// v6 per-layer prep: gWt [128][256], sW1t [512][128],
// w640t [3][128][640] (cols: k<512 -> 0.25*Wv remap, k>=512 -> Ws), bvmean.
__global__ void prep_layer_v6(
    const float* __restrict__ Ws, const float* __restrict__ gW,
    const float* __restrict__ sW1, const float* __restrict__ Wv,
    const float* __restrict__ bv,
    short* __restrict__ gWt, short* __restrict__ sW1t,
    short* __restrict__ w640t, float* __restrict__ bvmean)
{
    const int S0 = 32768;              // gWt
    const int S1 = S0 + 65536;         // sW1t
    const int S2 = S1 + 245760;        // w640t [3][128][640]
    const int S3 = S2 + 384;           // bvmean
    int id = blockIdx.x * blockDim.x + threadIdx.x;
    if (id < S0) {
        int n = id / 256, k = id - n * 256;
        gWt[id] = (short)f2bf(gW[k * 128 + n]);
    } else if (id < S1) {
        int q = id - S0;
        int h = q / 16384, rem = q - h * 16384;
        int n = rem / 128, k = rem - n * 128;
        sW1t[q] = (short)f2bf(sW1[(size_t)h * 16384 + k * 128 + n]);
    } else if (id < S2) {
        int q = id - S1;
        int r = q / 81920, rem = q - r * 81920;
        int d = rem / 640, k = rem - d * 640;
        float v;
        if (k < 512) {
            int hh = k >> 7, j = k & 127;
            v = 0.25f * Wv[(size_t)r * 65536 + j * 512 + hh * 128 + d];
        } else {
            v = Ws[(size_t)r * 16384 + (k - 512) * 128 + d];
        }
        w640t[q] = (short)f2bf(v);
    } else if (id < S3) {
        int q = id - S2;           // r*128 + d
        int r = q >> 7, d = q & 127;
        bvmean[q] = 0.25f * (bv[r * 512 + d] + bv[r * 512 + 128 + d]
                           + bv[r * 512 + 256 + d] + bv[r * 512 + 384 + d]);
    }
}

// ---------------------------------------------------------------------------
// G precompute v2: parallel + bank-safe. Grid (8 jg, 4 h, 6 lz) = 192 blocks.
// Writes G rows r*512+h*128+j of Wt4 [1536][128] and bias c[j].
// ---------------------------------------------------------------------------
__global__ __launch_bounds__(256) void gmat_v2(
    const float* __restrict__ Wq0, const float* __restrict__ Wk0, const float* __restrict__ bq0,
    const float* __restrict__ Wq1, const float* __restrict__ Wk1, const float* __restrict__ bq1,
    short* __restrict__ Wt4, float* __restrict__ B4)
{
    __shared__ float WqL[128 * 129];   // [i][d], pad 129 -> lane-i reads 2-way
    __shared__ float WkL[16 * 128];    // [jl][d], broadcast reads
    const int jg = blockIdx.x;         // 0..7 (16 j's each)
    const int h  = blockIdx.y;         // 0..3
    const int lz = blockIdx.z;         // 0..5
    const int l = lz / 3, r = lz - l * 3;
    const float* Wq = l ? Wq1 : Wq0;
    const float* Wk = l ? Wk1 : Wk0;
    const float* bq = l ? bq1 : bq0;
    short* Wt = Wt4 + (size_t)l * 196608;
    float* Bb = B4 + l * 1536;
    const float scale = 0.088388347648318447f;   // 1/sqrt(128)
    const int t = threadIdx.x;

    for (int v = t; v < 4096; v += 256) {
        int i = v >> 5, d4 = (v & 31) << 2;
        float4 q = *(const float4*)(Wq + (size_t)r * 65536 + i * 512 + h * 128 + d4);
        float* wp = WqL + i * 129 + d4;
        wp[0] = q.x; wp[1] = q.y; wp[2] = q.z; wp[3] = q.w;
    }
    for (int v = t; v < 512; v += 256) {
        int jl = v >> 5, d4 = (v & 31) << 2;
        float4 q = *(const float4*)(Wk + (size_t)r * 65536 + (jg * 16 + jl) * 512 + h * 128 + d4);
        float* wp = WkL + jl * 128 + d4;
        wp[0] = q.x; wp[1] = q.y; wp[2] = q.z; wp[3] = q.w;
    }
    __syncthreads();

    const int i = t & 127;
    const int jh = t >> 7;             // 0/1 (wave-uniform)
    const float* wk = WkL + jh * 8 * 128;
    float acc[8] = {0.f, 0.f, 0.f, 0.f, 0.f, 0.f, 0.f, 0.f};
    #pragma unroll 4
    for (int d = 0; d < 128; d++) {
        float wq = WqL[i * 129 + d];
        #pragma unroll
        for (int jj = 0; jj < 8; jj++)
            acc[jj] += wq * wk[jj * 128 + d];
    }
    short* wrow = Wt + ((size_t)(r * 512 + h * 128 + jg * 16 + jh * 8)) * 128 + i;
    #pragma unroll
    for (int jj = 0; jj < 8; jj++)
        wrow[(size_t)jj * 128] = (short)f2bf(scale * acc[jj]);

    if (t < 16) {
        const float* bqh = bq + r * 512 + h * 128;
        float c = 0.f;
        for (int d = 0; d < 128; d++) c += bqh[d] * WkL[t * 128 + d];
        Bb[r * 512 + h * 128 + jg * 16 + t] = scale * c;
    }
}

// --------------------------- CSR build (once) ------------------------------
__global__ void zero_i32_kernel(int* __restrict__ p, int n)
{
    int i = blockIdx.x * blockDim.x + threadIdx.x;
    if (i < n) p[i] = 0;
}

__global__ void hist3_kernel(const int* __restrict__ edges, int* __restrict__ cnt3)
{
    int i = blockIdx.x * blockDim.x + threadIdx.x;
    if (i >= 3 * EE) return;
    int r = i / EE, e = i - r * EE;
    int d = edges[(size_t)r * 2 * EE + EE + e];
    atomicAdd(&cnt3[r * Nn + d], 1);
}

__global__ __launch_bounds__(1024) void scan3_kernel(const int* __restrict__ cnt3,
                                                     int* __restrict__ rowptr3)
{
    __shared__ int part[1024];
    const int r = blockIdx.x;
    const int* cnt = cnt3 + r * Nn;
    int* rowptr = rowptr3 + r * (Nn + 1);
    int tid = threadIdx.x;
    int per = (Nn + 1023) >> 10;
    int base = tid * per;
    int s = 0;
    for (int i = 0; i < per; i++) {
        int idx = base + i;
        if (idx < Nn) s += cnt[idx];
    }
    part[tid] = s;
    __syncthreads();
    for (int off = 1; off < 1024; off <<= 1) {
        int val = (tid >= off) ? part[tid - off] : 0;
        __syncthreads();
        part[tid] += val;
        __syncthreads();
    }
    int excl = (tid == 0) ? 0 : part[tid - 1];
    for (int i = 0; i < per; i++) {
        int idx = base + i;
        if (idx < Nn) { rowptr[idx] = excl; excl += cnt[idx]; }
    }
    if (tid == 1023) rowptr[Nn] = part[1023];
}

__global__ void scatter3_kernel(const int* __restrict__ edges,
                                const int* __restrict__ rowptr3, int* __restrict__ fill3,
                                int* __restrict__ col3)
{
    int i = blockIdx.x * blockDim.x + threadIdx.x;
    if (i >= 3 * EE) return;
    int r = i / EE, e = i - r * EE;
    int src = edges[(size_t)r * 2 * EE + e];
    int d   = edges[(size_t)r * 2 * EE + EE + e];
    int pos = rowptr3[r * (Nn + 1) + d] + atomicAdd(&fill3[r * Nn + d], 1);
    col3[r * EE + pos] = src;
}

// --------------------------- classifier -----------------------------------
__global__ void clf_kernel(const float* __restrict__ t, const float* __restrict__ W,
                           const float* __restrict__ b, float* __restrict__ out, int M)
{
    int n = blockIdx.x * blockDim.x + threadIdx.x;
    if (n >= M) return;
    const float* row = t + (size_t)n * 128;
    float a0 = b[0], a1 = b[1];
    #pragma unroll
    for (int kk = 0; kk < 128; kk++) {
        float a = row[kk];
        a0 += a * W[kk * 2];
        a1 += a * W[kk * 2 + 1];
    }
    out[n * 2] = a0;
    out[n * 2 + 1] = a1;
}

// ---------------------------------------------------------------------------
extern "C" void kernel_launch(void* const* d_in, const int* in_sizes, int n_in,
                              void* d_out, int out_size, void* d_ws, size_t ws_size,
                              hipStream_t stream)
{
    const float* x      = (const float*)d_in[0];
    const int*   edges  = (const int*)d_in[1];
    const float* lin1_W = (const float*)d_in[2];
    const float* lin1_b = (const float*)d_in[3];
    const int L0 = 4, L1 = 17;
    const float* lin2_W = (const float*)d_in[30];
    const float* lin2_b = (const float*)d_in[31];
    const float* clf_W  = (const float*)d_in[32];
    const float* clf_b  = (const float*)d_in[33];
    float* out = (float*)d_out;

    char* w = (char*)d_ws;
    size_t off = 0;
    auto alloc = [&](size_t bytes) { void* p = w + off; off = (off + bytes + 255) & ~(size_t)255; return p; };
    float* h      = (float*)alloc((size_t)Nn * 128 * 4);     // 15.4 MB
    short* h_bf   = (short*)alloc((size_t)Nn * 128 * 2);     //  7.7 MB
    short* U_bf   = (short*)alloc((size_t)Nn * 384 * 2);     // 23.0 MB
    // BIG union (184.3 MB): qhat3 [3][N][512] + Ah3 [3][N][512] bf16
    //   <-> x_bf [N,768] bf16  <-> Hm [N,384] f32 + Hm_bf [N,384] bf16 <-> lin2o
    const size_t QH = (size_t)3 * Nn * 512 * 2;
    char* BIG     = (char*)alloc(2 * QH);
    short* qhat3  = (short*)BIG;
    short* Ah3    = (short*)(BIG + QH);
    short* x_bf   = (short*)BIG;
    float* Hm     = (float*)BIG;
    short* Hm_bf  = (short*)(BIG + (size_t)Nn * 384 * 4);
    float* lin2o  = (float*)BIG;
    short* lin1Wt = (short*)alloc((size_t)98304 * 2);
    short* lin2Wt = (short*)alloc((size_t)16384 * 2);
    short* qkvsWt4 = (short*)alloc((size_t)2 * 196608 * 2);  // [layer][1536][128] (G)
    short* gWt    = (short*)alloc((size_t)2 * 32768 * 2);
    short* sW1t   = (short*)alloc((size_t)2 * 65536 * 2);
    short* w640t  = (short*)alloc((size_t)2 * 245760 * 2);   // [layer][3][128][640]
    float* qkvsB4 = (float*)alloc((size_t)2 * 1536 * 4);
    float* bvmean = (float*)alloc((size_t)2 * 384 * 4);
    int* rowptr3  = (int*)alloc((size_t)3 * (Nn + 1) * 4);
    int* cnt3     = (int*)alloc((size_t)3 * Nn * 4);
    int* col3     = (int*)alloc((size_t)3 * EE * 4);
    float* partial = (float*)alloc((size_t)12 * MT_M * 4);
    float* scores = (float*)alloc(12 * 4);
    float* wmix   = (float*)alloc(3 * 4);

    const int MT = MT_M;    // 235
    dim3 blk(256);

    // ---- prep ----
    {
        int n_pairs = Nn * 768 / 2;
        convert_bf16_kernel<<<(n_pairs + 255) / 256, blk, 0, stream>>>(x, (unsigned*)x_bf, n_pairs);
        prep_global_kernel<<<(114688 + 255) / 256, blk, 0, stream>>>(lin1_W, lin2_W, lin1Wt, lin2Wt);
        for (int l = 0; l < 2; l++) {
            int base = (l == 0) ? L0 : L1;
            prep_layer_v6<<<(344448 + 255) / 256, blk, 0, stream>>>(
                (const float*)d_in[base + 6], (const float*)d_in[base + 8],
                (const float*)d_in[base + 10], (const float*)d_in[base + 4],
                (const float*)d_in[base + 5],
                gWt + (size_t)l * 32768, sW1t + (size_t)l * 65536,
                w640t + (size_t)l * 245760, bvmean + (size_t)l * 384);
        }
        gmat_v2<<<dim3(8, 4, 6), blk, 0, stream>>>(
            (const float*)d_in[L0 + 0], (const float*)d_in[L0 + 2], (const float*)d_in[L0 + 1],
            (const float*)d_in[L1 + 0], (const float*)d_in[L1 + 2], (const float*)d_in[L1 + 1],
            qkvsWt4, qkvsB4);
        zero_i32_kernel<<<(3 * Nn + 255) / 256, blk, 0, stream>>>(cnt3, 3 * Nn);
        hist3_kernel<<<(3 * EE + 255) / 256, blk, 0, stream>>>(edges, cnt3);
        scan3_kernel<<<3, 1024, 0, stream>>>(cnt3, rowptr3);
        zero_i32_kernel<<<(3 * Nn + 255) / 256, blk, 0, stream>>>(cnt3, 3 * Nn);
        scatter3_kernel<<<(3 * EE + 255) / 256, blk, 0, stream>>>(edges, rowptr3, cnt3, col3);
    }

    // lin1: h = lrelu(x @ lin1_W + b)   (x_bf in BIG; done before qhat overwrites)
    gemm_mfma<<<dim3(1, MT), blk, 0, stream>>>(
        x_bf, 768, x_bf, 768, KBIG, lin1Wt, lin1_b, h, 128, h_bf, 128, Nn, 768, 1);

    for (int l = 0; l < 2; l++) {
        int base = (l == 0) ? L0 : L1;
        const float* bs  = (const float*)d_in[base + 7];
        const float* gb  = (const float*)d_in[base + 9];
        const float* sb1 = (const float*)d_in[base + 11];
        const float* sw2 = (const float*)d_in[base + 12];
        short* lWt4   = qkvsWt4 + (size_t)l * 196608;
        short* lgWt   = gWt + (size_t)l * 32768;
        short* lsW1t  = sW1t + (size_t)l * 65536;
        short* lw640  = w640t + (size_t)l * 245760;
        float* lB4    = qkvsB4 + (size_t)l * 1536;
        float* lbvm   = bvmean + (size_t)l * 384;

        // qhat (3 rel x 512 cols)
        gemm_qkvs_v4<<<dim3(12, MT), blk, 0, stream>>>(
            h_bf, lWt4, lB4, qhat3, Nn);

        // attention in h-space: Ah = sum alpha * h[src]
        attn_v4<<<(3 * Nn + 3) / 4, blk, 0, stream>>>(qhat3, h_bf, rowptr3, col3, Ah3);

        // U = [Ah|h] @ w640 + bs + mask*bvmean  -> U_bf (no U-init pass, no U read)
        ufin_mfma<<<dim3(1, MT, 3), blk, 0, stream>>>(
            Ah3, h_bf, lw640, bs, lbvm, rowptr3, U_bf, Nn);

        // gate + combine (3 relations) -> Hm (fp32 + bf16)
        gate_mfma<<<dim3(1, MT, 3), blk, 0, stream>>>(
            U_bf, h_bf, lgWt, gb, h, Hm, Hm_bf, Nn);

        // semantic attention
        semantic_mfma<<<dim3(4, MT, 3), blk, 0, stream>>>(Hm_bf, lsW1t, sb1, sw2, partial, Nn);
        reduce12_kernel<<<12, 64, 0, stream>>>(partial, scores);
        compute_w_kernel<<<1, 64, 0, stream>>>(scores, wmix, 1.f / (float)Nn);
        mix_kernel<<<(Nn * 32 + 255) / 256, blk, 0, stream>>>(Hm, wmix, h, h_bf, Nn * 32);
    }

    // lin2 + lrelu -> lin2o (BIG region, Hm dead after mix)
    gemm_mfma<<<dim3(1, MT), blk, 0, stream>>>(
        h_bf, 128, h_bf, 128, KBIG, lin2Wt, lin2_b, lin2o, 128, (short*)nullptr, 0, Nn, 128, 1);
    clf_kernel<<<(Nn + 255) / 256, blk, 0, stream>>>(lin2o, clf_W, clf_b, out, Nn);
}